// Round 7
// baseline (321.939 us; speedup 1.0000x reference)
//
#include <hip/hip_runtime.h>
#include <cstdint>
#include <cstddef>

typedef unsigned short u16;
typedef __bf16 bf16x8 __attribute__((ext_vector_type(8)));
typedef float f32x4 __attribute__((ext_vector_type(4)));
typedef float f32x16 __attribute__((ext_vector_type(16)));

// ---------- constants ----------
#define BATCH 4
#define SEQ   2048
#define DM    768
#define NH    8
#define DK    96
#define DFF   2048
#define MTOK  8192          // BATCH*SEQ
#define QKVN  2304          // 3*DM
#define LOG2E 1.44269504088896340736f

// ---------- helpers ----------
__device__ __forceinline__ u16 f2bf(float f) {
  union { float f; uint32_t u; } v; v.f = f;
  return (u16)((v.u + 0x7fffu + ((v.u >> 16) & 1u)) >> 16);
}
__device__ __forceinline__ float bf2f(u16 b) {
  union { uint32_t u; float f; } v; v.u = (uint32_t)b << 16;
  return v.f;
}
__device__ __forceinline__ bf16x8 ld8(const u16* p) { return *(const bf16x8*)p; }
__device__ __forceinline__ void async16(const u16* g, u16* l) {
  __builtin_amdgcn_global_load_lds((const __attribute__((address_space(1))) void*)g,
                                   (__attribute__((address_space(3))) void*)l, 16, 0, 0);
}

// ---------- fused prep: cast_bf16 + concat3 + 6 weight transposes ----------
__global__ __launch_bounds__(256)
void prep(const float* __restrict__ x, u16* __restrict__ xb,
          const float* __restrict__ bq, const float* __restrict__ bk,
          const float* __restrict__ bv, float* __restrict__ bqkv,
          const float* __restrict__ Wq, const float* __restrict__ Wk,
          const float* __restrict__ Wv, const float* __restrict__ Wo,
          const float* __restrict__ W1, const float* __restrict__ W2,
          u16* __restrict__ WT, u16* __restrict__ WoT,
          u16* __restrict__ W1T, u16* __restrict__ W2T) {
  __shared__ float t[32][33];
  const int tid = threadIdx.x;
  int bid = blockIdx.x;

  if (bid < 6144) {                       // cast x (8192x768 fp32 -> bf16)
    size_t i = (size_t)bid * 1024 + tid * 4;
    float4 f = *(const float4*)(x + i);
    uint2 o;
    o.x = (unsigned)f2bf(f.x) | ((unsigned)f2bf(f.y) << 16);
    o.y = (unsigned)f2bf(f.z) | ((unsigned)f2bf(f.w) << 16);
    *(uint2*)(xb + i) = o;
    return;
  }
  if (bid < 6153) {                       // concat qkv bias (2304)
    int i = (bid - 6144) * 256 + tid;
    float v = (i < 768) ? bq[i] : (i < 1536) ? bk[i - 768] : bv[i - 1536];
    bqkv[i] = v;
    return;
  }
  bid -= 6153;
  const float* in; u16* out; int C, R, bx, by;
  if (bid < 576)       { in = Wq; out = WT;                 C = 768;  R = 768;  bx = bid % 24;          by = bid / 24; }
  else if (bid < 1152) { in = Wk; out = WT + 768 * 768;     C = 768;  R = 768;  bx = (bid - 576) % 24;  by = (bid - 576) / 24; }
  else if (bid < 1728) { in = Wv; out = WT + 2 * 768 * 768; C = 768;  R = 768;  bx = (bid - 1152) % 24; by = (bid - 1152) / 24; }
  else if (bid < 2304) { in = Wo; out = WoT;                C = 768;  R = 768;  bx = (bid - 1728) % 24; by = (bid - 1728) / 24; }
  else if (bid < 3840) { in = W1; out = W1T;                C = 2048; R = 768;  bx = (bid - 2304) % 64; by = (bid - 2304) / 64; }
  else                 { in = W2; out = W2T;                C = 768;  R = 2048; bx = (bid - 3840) % 24; by = (bid - 3840) / 24; }
  const int r0 = by * 32, c0 = bx * 32;
  const int tx = tid & 31, ty = tid >> 5;
#pragma unroll
  for (int i = 0; i < 4; i++)
    t[ty + i * 8][tx] = in[(size_t)(r0 + ty + i * 8) * C + c0 + tx];
  __syncthreads();
#pragma unroll
  for (int i = 0; i < 4; i++)
    out[(size_t)(c0 + ty + i * 8) * R + r0 + tx] = f2bf(t[tx][ty + i * 8]);
}

// v part of qkv (stride 2304) -> vt [B*H][96][2048] bf16
__global__ void transpose_v(const u16* __restrict__ v, u16* __restrict__ vt) {
  __shared__ u16 t[32][33];
  int bh = blockIdx.z, b = bh >> 3, h = bh & 7;
  int s0 = blockIdx.x * 32, d0 = blockIdx.y * 32;
  int tx = threadIdx.x, ty = threadIdx.y;
#pragma unroll
  for (int i = 0; i < 4; i++)
    t[ty + i * 8][tx] = v[(size_t)(b * SEQ + s0 + ty + i * 8) * QKVN + h * DK + d0 + tx];
  __syncthreads();
#pragma unroll
  for (int i = 0; i < 4; i++)
    vt[(size_t)(bh * DK + d0 + ty + i * 8) * SEQ + s0 + tx] = t[tx][ty + i * 8];
}

// ---------- GEMM 256x128 tile, 512 thr (8 waves 4Mx2N), XCD-swizzled ----------
// Round-6 post-mortem: GEMMs ~410 TF in the 2-barrier structure. 256-row
// tiles cut staged bytes/output 2.0->1.5 B per K-step and double B-panel L2
// reuse, with the identical (proven) fragment/swizzle inner loop.
// LDS 48KB; VGPR cap 128 (512,4) -> 2 blocks/CU = 16 waves/CU (same as before).
template <int RELU>
__global__ __launch_bounds__(512, 4)
void gemm_bt256(const u16* __restrict__ A, const u16* __restrict__ BT,
                const float* __restrict__ bias,
                u16* __restrict__ Cb, int N, int K) {
  __shared__ __align__(16) u16 lA[256 * 64];
  __shared__ __align__(16) u16 lB[128 * 64];
  const int tid = threadIdx.x;
  const int wave = tid >> 6, lane = tid & 63;
  const int quad = lane >> 4, l16 = lane & 15;
  const int wm = wave >> 1, wn = wave & 1;
  const int q8 = gridDim.x >> 3;
  const int wg = (blockIdx.x & 7) * q8 + (blockIdx.x >> 3);
  const int nbx = N >> 7;
  const int tm = (wg / nbx) * 256, tn = (wg % nbx) * 128;

  f32x4 acc[4][4] = {};

  for (int k0 = 0; k0 < K; k0 += 64) {
    __syncthreads();
#pragma unroll
    for (int i = 0; i < 4; i++) {              // A: 2048 chunks
      int cbase = i * 512 + wave * 64;
      int c = cbase + lane;
      int row = c >> 3;
      int scc = (c & 7) ^ (row & 7);
      async16(A + (size_t)(tm + row) * K + k0 + scc * 8, &lA[cbase * 8]);
    }
#pragma unroll
    for (int i = 0; i < 2; i++) {              // B: 1024 chunks
      int cbase = i * 512 + wave * 64;
      int c = cbase + lane;
      int row = c >> 3;
      int scc = (c & 7) ^ (row & 7);
      async16(BT + (size_t)(tn + row) * K + k0 + scc * 8, &lB[cbase * 8]);
    }
    __syncthreads();
#pragma unroll
    for (int ks = 0; ks < 2; ks++) {
      bf16x8 af[4], bfr[4];
#pragma unroll
      for (int i = 0; i < 4; i++) {
        int ra = wm * 64 + i * 16 + l16;
        af[i] = ld8(&lA[ra * 64 + (((ks * 4 + quad) ^ (ra & 7)) << 3)]);
      }
#pragma unroll
      for (int j = 0; j < 4; j++) {
        int rb = wn * 64 + j * 16 + l16;
        bfr[j] = ld8(&lB[rb * 64 + (((ks * 4 + quad) ^ (rb & 7)) << 3)]);
      }
#pragma unroll
      for (int i = 0; i < 4; i++)
#pragma unroll
        for (int j = 0; j < 4; j++)
          acc[i][j] = __builtin_amdgcn_mfma_f32_16x16x32_bf16(af[i], bfr[j], acc[i][j], 0, 0, 0);
    }
  }

#pragma unroll
  for (int i = 0; i < 4; i++) {
    const int row0 = tm + wm * 64 + i * 16 + quad * 4;
#pragma unroll
    for (int j = 0; j < 4; j++) {
      const int col = tn + wn * 64 + j * 16 + l16;
      const float bv = bias[col];
#pragma unroll
      for (int r = 0; r < 4; r++) {
        float v = acc[i][j][r] + bv;
        if (RELU) v = fmaxf(v, 0.f);
        Cb[(size_t)(row0 + r) * N + col] = f2bf(v);
      }
    }
  }
}

// ---------- GEMM 128x64 tile (N=768: 768 blocks), XCD-swizzled ----------
template <int RESID, int RELU, int OUTBF, int RESBF>
__global__ __launch_bounds__(256, 4)
void gemm_bt64(const u16* __restrict__ A, const u16* __restrict__ BT,
               const float* __restrict__ bias, const float* __restrict__ residf,
               const u16* __restrict__ residb,
               float* __restrict__ Cf, u16* __restrict__ Cb, int N, int K) {
  __shared__ __align__(16) u16 lA[128 * 64];
  __shared__ __align__(16) u16 lB[64 * 64];
  const int tid = threadIdx.x;
  const int wave = tid >> 6, lane = tid & 63;
  const int quad = lane >> 4, l16 = lane & 15;
  const int wm = wave >> 1, wn = wave & 1;
  const int q8 = gridDim.x >> 3;
  const int wg = (blockIdx.x & 7) * q8 + (blockIdx.x >> 3);
  const int nbx = N >> 6;
  const int tm = (wg / nbx) * 128, tn = (wg % nbx) * 64;

  f32x4 acc[4][2] = {};

  for (int k0 = 0; k0 < K; k0 += 64) {
    __syncthreads();
#pragma unroll
    for (int i = 0; i < 4; i++) {
      int cbase = (wave * 4 + i) * 64;
      int c = cbase + lane;
      int row = c >> 3;
      int scc = (c & 7) ^ (row & 7);
      async16(A + (size_t)(tm + row) * K + k0 + scc * 8, &lA[cbase * 8]);
    }
#pragma unroll
    for (int i = 0; i < 2; i++) {
      int cbase = (wave * 2 + i) * 64;
      int c = cbase + lane;
      int row = c >> 3;
      int scc = (c & 7) ^ (row & 7);
      async16(BT + (size_t)(tn + row) * K + k0 + scc * 8, &lB[cbase * 8]);
    }
    __syncthreads();
#pragma unroll
    for (int ks = 0; ks < 2; ks++) {
      bf16x8 af[4], bfr[2];
#pragma unroll
      for (int i = 0; i < 4; i++) {
        int ra = wm * 64 + i * 16 + l16;
        af[i] = ld8(&lA[ra * 64 + (((ks * 4 + quad) ^ (ra & 7)) << 3)]);
      }
#pragma unroll
      for (int j = 0; j < 2; j++) {
        int rb = wn * 32 + j * 16 + l16;
        bfr[j] = ld8(&lB[rb * 64 + (((ks * 4 + quad) ^ (rb & 7)) << 3)]);
      }
#pragma unroll
      for (int i = 0; i < 4; i++)
#pragma unroll
        for (int j = 0; j < 2; j++)
          acc[i][j] = __builtin_amdgcn_mfma_f32_16x16x32_bf16(af[i], bfr[j], acc[i][j], 0, 0, 0);
    }
  }

#pragma unroll
  for (int i = 0; i < 4; i++) {
    const int row0 = tm + wm * 64 + i * 16 + quad * 4;
#pragma unroll
    for (int j = 0; j < 2; j++) {
      const int col = tn + wn * 32 + j * 16 + l16;
      const float bv = bias[col];
#pragma unroll
      for (int r = 0; r < 4; r++) {
        float v = acc[i][j][r] + bv;
        if (RESID) {
          if (RESBF) v += bf2f(residb[(size_t)(row0 + r) * N + col]);
          else       v += residf[(size_t)(row0 + r) * N + col];
        }
        if (RELU) v = fmaxf(v, 0.f);
        if (OUTBF) Cb[(size_t)(row0 + r) * N + col] = f2bf(v);
        else       Cf[(size_t)(row0 + r) * N + col] = v;
      }
    }
  }
}

// ---------- flash attention v14: V-dbuf, 3 blocks/CU (24 waves/CU) ----------
// Round-6 post-mortem: VGPR 64 but LDS 63.5KB capped occupancy at 2 blocks/CU.
// V triple->double buffer: LDS 51,200 B -> 3 blocks/CU = 6 waves/SIMD.
// Pipeline kept via barrier split:
//   { barA(drain t); QK(t); PV(t-1); barB; stage(t+1); SM(t)->pa }
// barB protects V[(t+1)&1] (just read by PV(t-1)) and K[(t+1)&1] (read two
// barriers ago by QK(t-1)). Barrier waits overlap across the 3 blocks/CU.
#define KROW 104  // u16 per K row (13 slots of 8)
#define VROW 64   // u16 per V row (8 slots of 8, XOR-swizzled)

// pack one 16-key slice (8 f32 score regs) into one PV B-fragment.
#define PACK_SLICE(SC, B, DST)                                                   \
  {                                                                              \
    uint32_t u0, u1, u2, u3;                                                     \
    asm("v_cvt_pk_bf16_f32 %0, %1, %2" : "=v"(u0) : "v"(SC[B+0]), "v"(SC[B+1])); \
    asm("v_cvt_pk_bf16_f32 %0, %1, %2" : "=v"(u1) : "v"(SC[B+2]), "v"(SC[B+3])); \
    asm("v_cvt_pk_bf16_f32 %0, %1, %2" : "=v"(u2) : "v"(SC[B+4]), "v"(SC[B+5])); \
    asm("v_cvt_pk_bf16_f32 %0, %1, %2" : "=v"(u3) : "v"(SC[B+6]), "v"(SC[B+7])); \
    asm("v_permlane32_swap_b32 %0, %1" : "+v"(u2), "+v"(u0));                    \
    asm("v_permlane32_swap_b32 %0, %1" : "+v"(u3), "+v"(u1));                    \
    union { uint32_t w[4]; bf16x8 v; } pu_;                                      \
    pu_.w[0] = u0; pu_.w[1] = u1; pu_.w[2] = u2; pu_.w[3] = u3;                  \
    DST = pu_.v;                                                                 \
  }

__global__ __launch_bounds__(512)
void flash_attn(const u16* __restrict__ qkv, const u16* __restrict__ Vt,
                u16* __restrict__ Ob) {
  // flat LDS: K bufs [2][64*104] u16 (26,624 B) at 0; V bufs [2][96*64] u16
  // (24,576 B) at u16-offset 13312. Total 51,200 B -> 3 blocks/CU.
  __shared__ __align__(16) u16 smem[25600];
  const int tid = threadIdx.x, wave = tid >> 6, lane = tid & 63;
  const int l32 = lane & 31, half = lane >> 5;
  const int qsub = wave >> 1, kodd = wave & 1, pair = wave >> 1;
  // XCD-aware decode: lin%8 = XCD; 4 heads/XCD; 16 q-blocks per head.
  const int lin = blockIdx.x;
  const int bh = (lin & 7) * 4 + ((lin >> 3) & 3);
  const int qb = lin >> 5;
  const int b = bh >> 3, h = bh & 7;
  const int q0 = qb * 128 + qsub * 32;
  const u16* Qp = qkv;
  const u16* KpB = qkv + 768 + (size_t)b * SEQ * QKVN + h * DK;
  const u16* VtB = Vt + (size_t)bh * DK * SEQ;
  const float cs = 0.10206207262f * LOG2E;  // (1/sqrt(96)) * log2(e)
  const float Ms = 16.0f * cs;              // fixed shift (folded)

  // Q^T B-fragments: lane holds q = l32, dk = d*16 + half*8 + [0..7]
  bf16x8 qf[6];
#pragma unroll
  for (int d = 0; d < 6; d++)
    qf[d] = ld8(Qp + (size_t)(b * SEQ + q0 + l32) * QKVN + h * DK + d * 16 + half * 8);

  f32x16 of[3] = {};     // O^T partial (this wave's 32-key half): D[dk blk][q=l32]
  float lp[4] = {0.f, 0.f, 0.f, 0.f};  // 4 independent softmax-denom partials
  bf16x8 pa[2];          // packed P fragments carried body->body

  // DMA one K/V tile with 512 threads:
  // K = 832 chunks [64 rows][13 slots] (slot s holds chunk min(s,11));
  // V = 768 chunks [96 rows][8 slots]  (slot s holds chunk (s^row)&7).
  auto stage = [&](int kt, int buf) {
    u16* kd = smem + buf * 6656;
    u16* vd = smem + 13312 + buf * 6144;
    {
      int sl = tid;                        // 0..511
      int row = sl / 13, s = sl - row * 13;
      int c = s > 11 ? 11 : s;
      async16(KpB + (size_t)(kt + row) * QKVN + c * 8, kd + sl * 8);
    }
    if (tid < 320) {
      int sl = 512 + tid;                  // 512..831
      int row = sl / 13, s = sl - row * 13;
      int c = s > 11 ? 11 : s;
      async16(KpB + (size_t)(kt + row) * QKVN + c * 8, kd + sl * 8);
    }
    {
      int s = tid;
      int row = s >> 3, c = (s ^ row) & 7;
      async16(VtB + (size_t)row * SEQ + kt + c * 8, vd + s * 8);
    }
    if (tid < 256) {
      int s = 512 + tid;
      int row = s >> 3, c = (s ^ row) & 7;
      async16(VtB + (size_t)row * SEQ + kt + c * 8, vd + s * 8);
    }
  };

  stage(0, 0);
  const int krow = kodd * 32 + l32;

  for (int t = 0; t < 32; t++) {
    __syncthreads();  // barA: tile t DMA drained

    // QK(t): S^T = K Q^T for this wave's 32-key half; col = q
    const u16* kd = smem + (t & 1) * 6656;
    f32x16 sc = {};
    __builtin_amdgcn_s_setprio(1);
#pragma unroll
    for (int d = 0; d < 6; d++) {
      bf16x8 kb = ld8(&kd[krow * KROW + (d * 2 + half) * 8]);  // identity slot
      sc = __builtin_amdgcn_mfma_f32_32x32x16_bf16(kb, qf[d], sc, 0, 0, 0);
    }

    // PV(t-1): O^T += V^T P^T (independent of QK(t) -> overlaps)
    if (t > 0) {
      const u16* vd = smem + 13312 + ((t - 1) & 1) * 6144;
#pragma unroll
      for (int ks = 0; ks < 2; ks++) {
        int gv = kodd * 4 + ks * 2 + half;
#pragma unroll
        for (int db = 0; db < 3; db++) {
          int vrow = db * 32 + l32;
          bf16x8 va = ld8(&vd[vrow * VROW + ((gv ^ vrow) & 7) * 8]);
          of[db] = __builtin_amdgcn_mfma_f32_32x32x16_bf16(va, pa[ks], of[db], 0, 0, 0);
        }
      }
    }
    __builtin_amdgcn_s_setprio(0);

    __syncthreads();  // barB: buf (t+1)&1 reads (QK(t-1), PV(t-1)) complete
    if (t + 1 < 32) stage((t + 1) * 64, (t + 1) & 1);

    // SM(t): P = exp2(s*cs - Ms); 4 independent l chains; pack into pa
#pragma unroll
    for (int r = 0; r < 16; r++) {
      float p = __builtin_amdgcn_exp2f(sc[r] * cs - Ms);
      lp[r & 3] += p;
      sc[r] = p;
    }
    PACK_SLICE(sc, 0, pa[0])
    PACK_SLICE(sc, 8, pa[1])
  }

  // tail: PV(31) (V buf 1 staged at t=30, drained at barA t=31, unmodified)
  {
    const u16* vd = smem + 13312 + 6144;
#pragma unroll
    for (int ks = 0; ks < 2; ks++) {
      int gv = kodd * 4 + ks * 2 + half;
#pragma unroll
      for (int db = 0; db < 3; db++) {
        int vrow = db * 32 + l32;
        bf16x8 va = ld8(&vd[vrow * VROW + ((gv ^ vrow) & 7) * 8]);
        of[db] = __builtin_amdgcn_mfma_f32_32x32x16_bf16(va, pa[ks], of[db], 0, 0, 0);
      }
    }
  }

  // ---- epilogue: wave-pair combine via LDS, divide, store ----
  float l_lane = (lp[0] + lp[1]) + (lp[2] + lp[3]);
  float lw = l_lane + __shfl_xor(l_lane, 32);   // this wave's l per q=l32
  float linv = 0.f;
  float* xf = (float*)smem;
  const int q = q0 + l32;
  u16* Orow = Ob + (size_t)(b * SEQ + q) * DM + h * DK;

  __syncthreads();                               // S1: loop done, smem free
  if (kodd) {                                    // phase A write: of[0,1] + lw
    float* dst = xf + (pair * 64 + lane) * 33;
#pragma unroll
    for (int r = 0; r < 16; r++) { dst[r] = of[0][r]; dst[16 + r] = of[1][r]; }
    dst[32] = lw;
  }
  __syncthreads();                               // S2
  if (!kodd) {
    const float* src = xf + (pair * 64 + lane) * 33;
    linv = 1.f / (lw + src[32]);
#pragma unroll
    for (int db = 0; db < 2; db++)
#pragma unroll
      for (int r = 0; r < 16; r++) {
        int dk = db * 32 + (r & 3) + 8 * (r >> 2) + 4 * half;
        Orow[dk] = f2bf((of[db][r] + src[db * 16 + r]) * linv);
      }
  }
  __syncthreads();                               // S3: phase A reads done
  if (kodd) {                                    // phase B write: of[2]
    float* dst = xf + (pair * 64 + lane) * 16;
#pragma unroll
    for (int r = 0; r < 16; r++) dst[r] = of[2][r];
  }
  __syncthreads();                               // S4
  if (!kodd) {
    const float* src = xf + (pair * 64 + lane) * 16;
#pragma unroll
    for (int r = 0; r < 16; r++) {
      int dk = 64 + (r & 3) + 8 * (r >> 2) + 4 * half;
      Orow[dk] = f2bf((of[2][r] + src[r]) * linv);
    }
  }
}

// ---------- LayerNorm: out = LN(y); outf and/or outb optional ----------
__global__ __launch_bounds__(256)
void ln_kernel(const float* __restrict__ y, const float* __restrict__ g,
               const float* __restrict__ be, float* __restrict__ outf,
               u16* __restrict__ outb) {
  int row = blockIdx.x, t = threadIdx.x;
  const float* yr = y + (size_t)row * DM;
  float v[3], s = 0.f, s2 = 0.f;
#pragma unroll
  for (int i = 0; i < 3; i++) {
    v[i] = yr[t + i * 256];
    s += v[i];
    s2 += v[i] * v[i];
  }
#pragma unroll
  for (int m = 1; m < 64; m <<= 1) {
    s += __shfl_xor(s, m);
    s2 += __shfl_xor(s2, m);
  }
  __shared__ float red[2][4];
  int w = t >> 6;
  if ((t & 63) == 0) { red[0][w] = s; red[1][w] = s2; }
  __syncthreads();
  s = red[0][0] + red[0][1] + red[0][2] + red[0][3];
  s2 = red[1][0] + red[1][1] + red[1][2] + red[1][3];
  float mu = s * (1.f / DM);
  float var = s2 * (1.f / DM) - mu * mu;
  float rs = rsqrtf(var + 1e-5f);
#pragma unroll
  for (int i = 0; i < 3; i++) {
    int e = t + i * 256;
    float o = (v[i] - mu) * rs * g[e] + be[e];
    if (outf) outf[(size_t)row * DM + e] = o;
    if (outb) outb[(size_t)row * DM + e] = f2bf(o);
  }
}

// ---------- workspace layout (bytes) ----------
#define SZ_BF 12582912ull            // 8192*768*2
#define SZ_F  25165824ull            // 8192*768*4
#define O_XB   0ull                                  // x bf16; later attn_out
#define O_WT   (O_XB + SZ_BF)                        // qkv^T concat [2304][768] bf16
#define O_WOT  (O_WT + 3538944ull)
#define O_W1T  (O_WOT + 1179648ull)
#define O_W2T  (O_W1T + 3145728ull)
#define O_QKV  (O_W2T + 3145728ull)                  // [8192][2304] bf16; later x1b + h
#define O_VT   (O_QKV + 37748736ull)                 // [32][96][2048] bf16
#define O_Y    (O_VT + SZ_BF)                        // fp32 pre-LN buffer
#define O_X1F  (O_Y + SZ_F)                          // (unused now)
#define O_BIAS (O_X1F + SZ_F)                        // 2304 fp32 concat qkv bias

extern "C" void kernel_launch(void* const* d_in, const int* in_sizes, int n_in,
                              void* d_out, int out_size, void* d_ws, size_t ws_size,
                              hipStream_t stream) {
  const float* x   = (const float*)d_in[0];
  const float* Wq  = (const float*)d_in[1];
  const float* bq  = (const float*)d_in[2];
  const float* Wk  = (const float*)d_in[3];
  const float* bk  = (const float*)d_in[4];
  const float* Wv  = (const float*)d_in[5];
  const float* bv  = (const float*)d_in[6];
  const float* Wo  = (const float*)d_in[7];
  const float* bo  = (const float*)d_in[8];
  const float* g1  = (const float*)d_in[9];
  const float* be1 = (const float*)d_in[10];
  const float* W1  = (const float*)d_in[11];
  const float* b1  = (const float*)d_in[12];
  const float* W2  = (const float*)d_in[13];
  const float* b2  = (const float*)d_in[14];
  const float* g2  = (const float*)d_in[15];
  const float* be2 = (const float*)d_in[16];
  float* out = (float*)d_out;
  char* ws = (char*)d_ws;

  u16* xb    = (u16*)(ws + O_XB);
  u16* WT    = (u16*)(ws + O_WT);
  u16* WoT   = (u16*)(ws + O_WOT);
  u16* W1T   = (u16*)(ws + O_W1T);
  u16* W2T   = (u16*)(ws + O_W2T);
  u16* qkv   = (u16*)(ws + O_QKV);
  u16* vt    = (u16*)(ws + O_VT);
  float* y   = (float*)(ws + O_Y);
  float* bqkv = (float*)(ws + O_BIAS);
  u16* ao   = xb;                       // alias: xb dead after QKV GEMM
  u16* x1b  = qkv;                      // alias: qkv dead after attention
  u16* hbuf = qkv + (size_t)MTOK * DM;  // h [8192][2048] bf16

  // fused prep (one dispatch)
  prep<<<11529, 256, 0, stream>>>(x, xb, bq, bk, bv, bqkv,
                                  Wq, Wk, Wv, Wo, W1, W2,
                                  WT, WoT, W1T, W2T);

  // QKV projection (fused N=2304): 256x128 tiles, 576 blocks, swizzled
  gemm_bt256<0><<<576, 512, 0, stream>>>(xb, WT, bqkv, qkv, QKVN, DM);
  // V^T for PV A-operand
  transpose_v<<<dim3(64, 3, 32), dim3(32, 8), 0, stream>>>(qkv + 1536, vt);
  // attention: 512 blocks x 512 threads (8 waves: 4 q-subs x 2 key-halves)
  flash_attn<<<512, 512, 0, stream>>>(qkv, vt, ao);
  // out projection + residual(x fp32) -> y (fp32): 12x64 tiles, swizzled
  gemm_bt64<1, 0, 0, 0><<<768, 256, 0, stream>>>(ao, WoT, bo, x, nullptr, y, nullptr, DM, DM);
  // LN1 -> x1b (bf16 only; fp32 x1 round-trip eliminated)
  ln_kernel<<<8192, 256, 0, stream>>>(y, g1, be1, nullptr, x1b);
  // FFN1 + ReLU -> h (bf16): 256x128 tiles, 512 blocks, swizzled
  gemm_bt256<1><<<512, 512, 0, stream>>>(x1b, W1T, b1, hbuf, DFF, DM);
  // FFN2 + residual(x1b bf16) -> y (fp32): 12x64 tiles, swizzled
  gemm_bt64<1, 0, 0, 1><<<768, 256, 0, stream>>>(hbuf, W2T, b2, nullptr, x1b, y, nullptr, DM, DFF);
  // LN2 -> out
  ln_kernel<<<8192, 256, 0, stream>>>(y, g2, be2, out, nullptr);
}

// Round 10
// 317.510 us; speedup vs baseline: 1.0139x; 1.0139x over previous
//
#include <hip/hip_runtime.h>
#include <cstdint>
#include <cstddef>

typedef unsigned short u16;
typedef __bf16 bf16x8 __attribute__((ext_vector_type(8)));
typedef float f32x4 __attribute__((ext_vector_type(4)));
typedef float f32x16 __attribute__((ext_vector_type(16)));

// ---------- constants ----------
#define BATCH 4
#define SEQ   2048
#define DM    768
#define NH    8
#define DK    96
#define DFF   2048
#define MTOK  8192          // BATCH*SEQ
#define QKVN  2304          // 3*DM
#define LOG2E 1.44269504088896340736f

// ---------- helpers ----------
__device__ __forceinline__ u16 f2bf(float f) {
  union { float f; uint32_t u; } v; v.f = f;
  return (u16)((v.u + 0x7fffu + ((v.u >> 16) & 1u)) >> 16);
}
__device__ __forceinline__ float bf2f(u16 b) {
  union { uint32_t u; float f; } v; v.u = (uint32_t)b << 16;
  return v.f;
}
__device__ __forceinline__ bf16x8 ld8(const u16* p) { return *(const bf16x8*)p; }
__device__ __forceinline__ void async16(const u16* g, u16* l) {
  __builtin_amdgcn_global_load_lds((const __attribute__((address_space(1))) void*)g,
                                   (__attribute__((address_space(3))) void*)l, 16, 0, 0);
}

// ---------- fused prep: cast_bf16 + concat3 + 6 weight transposes ----------
__global__ __launch_bounds__(256)
void prep(const float* __restrict__ x, u16* __restrict__ xb,
          const float* __restrict__ bq, const float* __restrict__ bk,
          const float* __restrict__ bv, float* __restrict__ bqkv,
          const float* __restrict__ Wq, const float* __restrict__ Wk,
          const float* __restrict__ Wv, const float* __restrict__ Wo,
          const float* __restrict__ W1, const float* __restrict__ W2,
          u16* __restrict__ WT, u16* __restrict__ WoT,
          u16* __restrict__ W1T, u16* __restrict__ W2T) {
  __shared__ float t[32][33];
  const int tid = threadIdx.x;
  int bid = blockIdx.x;

  if (bid < 6144) {                       // cast x (8192x768 fp32 -> bf16)
    size_t i = (size_t)bid * 1024 + tid * 4;
    float4 f = *(const float4*)(x + i);
    uint2 o;
    o.x = (unsigned)f2bf(f.x) | ((unsigned)f2bf(f.y) << 16);
    o.y = (unsigned)f2bf(f.z) | ((unsigned)f2bf(f.w) << 16);
    *(uint2*)(xb + i) = o;
    return;
  }
  if (bid < 6153) {                       // concat qkv bias (2304)
    int i = (bid - 6144) * 256 + tid;
    float v = (i < 768) ? bq[i] : (i < 1536) ? bk[i - 768] : bv[i - 1536];
    bqkv[i] = v;
    return;
  }
  bid -= 6153;
  const float* in; u16* out; int C, R, bx, by;
  if (bid < 576)       { in = Wq; out = WT;                 C = 768;  R = 768;  bx = bid % 24;          by = bid / 24; }
  else if (bid < 1152) { in = Wk; out = WT + 768 * 768;     C = 768;  R = 768;  bx = (bid - 576) % 24;  by = (bid - 576) / 24; }
  else if (bid < 1728) { in = Wv; out = WT + 2 * 768 * 768; C = 768;  R = 768;  bx = (bid - 1152) % 24; by = (bid - 1152) / 24; }
  else if (bid < 2304) { in = Wo; out = WoT;                C = 768;  R = 768;  bx = (bid - 1728) % 24; by = (bid - 1728) / 24; }
  else if (bid < 3840) { in = W1; out = W1T;                C = 2048; R = 768;  bx = (bid - 2304) % 64; by = (bid - 2304) / 64; }
  else                 { in = W2; out = W2T;                C = 768;  R = 2048; bx = (bid - 3840) % 24; by = (bid - 3840) / 24; }
  const int r0 = by * 32, c0 = bx * 32;
  const int tx = tid & 31, ty = tid >> 5;
#pragma unroll
  for (int i = 0; i < 4; i++)
    t[ty + i * 8][tx] = in[(size_t)(r0 + ty + i * 8) * C + c0 + tx];
  __syncthreads();
#pragma unroll
  for (int i = 0; i < 4; i++)
    out[(size_t)(c0 + ty + i * 8) * R + r0 + tx] = f2bf(t[tx][ty + i * 8]);
}

// v part of qkv (stride 2304) -> vt [B*H][96][2048] bf16
__global__ void transpose_v(const u16* __restrict__ v, u16* __restrict__ vt) {
  __shared__ u16 t[32][33];
  int bh = blockIdx.z, b = bh >> 3, h = bh & 7;
  int s0 = blockIdx.x * 32, d0 = blockIdx.y * 32;
  int tx = threadIdx.x, ty = threadIdx.y;
#pragma unroll
  for (int i = 0; i < 4; i++)
    t[ty + i * 8][tx] = v[(size_t)(b * SEQ + s0 + ty + i * 8) * QKVN + h * DK + d0 + tx];
  __syncthreads();
#pragma unroll
  for (int i = 0; i < 4; i++)
    vt[(size_t)(bh * DK + d0 + ty + i * 8) * SEQ + s0 + tx] = t[tx][ty + i * 8];
}

// ---------- GEMM: C[M,N] = A[M,K] @ BT[N,K]^T + bias (+resid)(+relu) ----------
// 1-D grid + XCD-chunked bijective swizzle (T1, m204). Single-buffer 2-barrier
// loop (proven; R8/R9 dbuf variants both failed to bench -> retired).
template <int RESID, int RELU, int OUTBF>
__global__ __launch_bounds__(256, 4)
void gemm_bt(const u16* __restrict__ A, const u16* __restrict__ BT,
             const float* __restrict__ bias, const float* __restrict__ resid,
             float* __restrict__ Cf, u16* __restrict__ Cb, int N, int K) {
  __shared__ __align__(16) u16 lA[128 * 64];
  __shared__ __align__(16) u16 lB[128 * 64];
  const int tid = threadIdx.x;
  const int wave = tid >> 6, lane = tid & 63;
  const int quad = lane >> 4, l16 = lane & 15;
  const int wm = wave >> 1, wn = wave & 1;
  const int q8 = gridDim.x >> 3;
  const int wg = (blockIdx.x & 7) * q8 + (blockIdx.x >> 3);
  const int nbx = N >> 7;
  const int tm = (wg / nbx) * 128, tn = (wg % nbx) * 128;

  f32x4 acc[4][4] = {};

  for (int k0 = 0; k0 < K; k0 += 64) {
    __syncthreads();
#pragma unroll
    for (int i = 0; i < 4; i++) {
      int cbase = (wave * 4 + i) * 64;
      int c = cbase + lane;
      int row = c >> 3;
      int scc = (c & 7) ^ (row & 7);           // XOR swizzle of 16B chunks
      async16(A + (size_t)(tm + row) * K + k0 + scc * 8, &lA[cbase * 8]);
      async16(BT + (size_t)(tn + row) * K + k0 + scc * 8, &lB[cbase * 8]);
    }
    __syncthreads();
#pragma unroll
    for (int ks = 0; ks < 2; ks++) {
      bf16x8 af[4], bfr[4];
#pragma unroll
      for (int i = 0; i < 4; i++) {
        int ra = wm * 64 + i * 16 + l16;
        af[i] = ld8(&lA[ra * 64 + (((ks * 4 + quad) ^ (ra & 7)) << 3)]);
        int rb = wn * 64 + i * 16 + l16;
        bfr[i] = ld8(&lB[rb * 64 + (((ks * 4 + quad) ^ (rb & 7)) << 3)]);
      }
#pragma unroll
      for (int i = 0; i < 4; i++)
#pragma unroll
        for (int j = 0; j < 4; j++)
          acc[i][j] = __builtin_amdgcn_mfma_f32_16x16x32_bf16(af[i], bfr[j], acc[i][j], 0, 0, 0);
    }
  }

#pragma unroll
  for (int i = 0; i < 4; i++) {
    const int row0 = tm + wm * 64 + i * 16 + quad * 4;
#pragma unroll
    for (int j = 0; j < 4; j++) {
      const int col = tn + wn * 64 + j * 16 + l16;
      const float bv = bias[col];
#pragma unroll
      for (int r = 0; r < 4; r++) {
        float v = acc[i][j][r] + bv;
        if (RESID) v += resid[(size_t)(row0 + r) * N + col];
        if (RELU) v = fmaxf(v, 0.f);
        if (OUTBF) Cb[(size_t)(row0 + r) * N + col] = f2bf(v);
        else       Cf[(size_t)(row0 + r) * N + col] = v;
      }
    }
  }
}

// ---------- GEMM 128x64 tile (N=768: 768 blocks), XCD-swizzled ----------
template <int RESID, int RELU, int OUTBF, int RESBF>
__global__ __launch_bounds__(256, 4)
void gemm_bt64(const u16* __restrict__ A, const u16* __restrict__ BT,
               const float* __restrict__ bias, const float* __restrict__ residf,
               const u16* __restrict__ residb,
               float* __restrict__ Cf, u16* __restrict__ Cb, int N, int K) {
  __shared__ __align__(16) u16 lA[128 * 64];
  __shared__ __align__(16) u16 lB[64 * 64];
  const int tid = threadIdx.x;
  const int wave = tid >> 6, lane = tid & 63;
  const int quad = lane >> 4, l16 = lane & 15;
  const int wm = wave >> 1, wn = wave & 1;
  const int q8 = gridDim.x >> 3;
  const int wg = (blockIdx.x & 7) * q8 + (blockIdx.x >> 3);
  const int nbx = N >> 6;
  const int tm = (wg / nbx) * 128, tn = (wg % nbx) * 64;

  f32x4 acc[4][2] = {};

  for (int k0 = 0; k0 < K; k0 += 64) {
    __syncthreads();
#pragma unroll
    for (int i = 0; i < 4; i++) {
      int cbase = (wave * 4 + i) * 64;
      int c = cbase + lane;
      int row = c >> 3;
      int scc = (c & 7) ^ (row & 7);
      async16(A + (size_t)(tm + row) * K + k0 + scc * 8, &lA[cbase * 8]);
    }
#pragma unroll
    for (int i = 0; i < 2; i++) {
      int cbase = (wave * 2 + i) * 64;
      int c = cbase + lane;
      int row = c >> 3;
      int scc = (c & 7) ^ (row & 7);
      async16(BT + (size_t)(tn + row) * K + k0 + scc * 8, &lB[cbase * 8]);
    }
    __syncthreads();
#pragma unroll
    for (int ks = 0; ks < 2; ks++) {
      bf16x8 af[4], bfr[2];
#pragma unroll
      for (int i = 0; i < 4; i++) {
        int ra = wm * 64 + i * 16 + l16;
        af[i] = ld8(&lA[ra * 64 + (((ks * 4 + quad) ^ (ra & 7)) << 3)]);
      }
#pragma unroll
      for (int j = 0; j < 2; j++) {
        int rb = wn * 32 + j * 16 + l16;
        bfr[j] = ld8(&lB[rb * 64 + (((ks * 4 + quad) ^ (rb & 7)) << 3)]);
      }
#pragma unroll
      for (int i = 0; i < 4; i++)
#pragma unroll
        for (int j = 0; j < 2; j++)
          acc[i][j] = __builtin_amdgcn_mfma_f32_16x16x32_bf16(af[i], bfr[j], acc[i][j], 0, 0, 0);
    }
  }

#pragma unroll
  for (int i = 0; i < 4; i++) {
    const int row0 = tm + wm * 64 + i * 16 + quad * 4;
#pragma unroll
    for (int j = 0; j < 2; j++) {
      const int col = tn + wn * 32 + j * 16 + l16;
      const float bv = bias[col];
#pragma unroll
      for (int r = 0; r < 4; r++) {
        float v = acc[i][j][r] + bv;
        if (RESID) {
          if (RESBF) v += bf2f(residb[(size_t)(row0 + r) * N + col]);
          else       v += residf[(size_t)(row0 + r) * N + col];
        }
        if (RELU) v = fmaxf(v, 0.f);
        if (OUTBF) Cb[(size_t)(row0 + r) * N + col] = f2bf(v);
        else       Cf[(size_t)(row0 + r) * N + col] = v;
      }
    }
  }
}

// ---------- flash attention v13: pipelined QK(t) || PV(t-1), 4-way l ----------
#define KROW 104  // u16 per K row (13 slots of 8)
#define VROW 64   // u16 per V row (8 slots of 8, XOR-swizzled)

// pack one 16-key slice (8 f32 score regs) into one PV B-fragment.
#define PACK_SLICE(SC, B, DST)                                                   \
  {                                                                              \
    uint32_t u0, u1, u2, u3;                                                     \
    asm("v_cvt_pk_bf16_f32 %0, %1, %2" : "=v"(u0) : "v"(SC[B+0]), "v"(SC[B+1])); \
    asm("v_cvt_pk_bf16_f32 %0, %1, %2" : "=v"(u1) : "v"(SC[B+2]), "v"(SC[B+3])); \
    asm("v_cvt_pk_bf16_f32 %0, %1, %2" : "=v"(u2) : "v"(SC[B+4]), "v"(SC[B+5])); \
    asm("v_cvt_pk_bf16_f32 %0, %1, %2" : "=v"(u3) : "v"(SC[B+6]), "v"(SC[B+7])); \
    asm("v_permlane32_swap_b32 %0, %1" : "+v"(u2), "+v"(u0));                    \
    asm("v_permlane32_swap_b32 %0, %1" : "+v"(u3), "+v"(u1));                    \
    union { uint32_t w[4]; bf16x8 v; } pu_;                                      \
    pu_.w[0] = u0; pu_.w[1] = u1; pu_.w[2] = u2; pu_.w[3] = u3;                  \
    DST = pu_.v;                                                                 \
  }

__global__ __launch_bounds__(512, 4)
void flash_attn(const u16* __restrict__ qkv, const u16* __restrict__ Vt,
                u16* __restrict__ Ob) {
  // flat LDS: K bufs [2][64*104] u16 (26,624 B), V bufs [3][96*64] u16
  // (36,864 B); total 63,488 B. Epilogue aliases as float exchange.
  __shared__ __align__(16) u16 smem[31744];
  const int tid = threadIdx.x, wave = tid >> 6, lane = tid & 63;
  const int l32 = lane & 31, half = lane >> 5;
  const int qsub = wave >> 1, kodd = wave & 1, pair = wave >> 1;
  // XCD-aware decode: lin%8 = XCD; 4 heads/XCD; 16 q-blocks per head.
  const int lin = blockIdx.x;
  const int bh = (lin & 7) * 4 + ((lin >> 3) & 3);
  const int qb = lin >> 5;
  const int b = bh >> 3, h = bh & 7;
  const int q0 = qb * 128 + qsub * 32;
  const u16* Qp = qkv;
  const u16* KpB = qkv + 768 + (size_t)b * SEQ * QKVN + h * DK;
  const u16* VtB = Vt + (size_t)bh * DK * SEQ;
  const float cs = 0.10206207262f * LOG2E;  // (1/sqrt(96)) * log2(e)
  const float Ms = 16.0f * cs;              // fixed shift (folded)

  // Q^T B-fragments: lane holds q = l32, dk = d*16 + half*8 + [0..7]
  bf16x8 qf[6];
#pragma unroll
  for (int d = 0; d < 6; d++)
    qf[d] = ld8(Qp + (size_t)(b * SEQ + q0 + l32) * QKVN + h * DK + d * 16 + half * 8);

  f32x16 of[3] = {};     // O^T partial (this wave's 32-key half): D[dk blk][q=l32]
  float lp[4] = {0.f, 0.f, 0.f, 0.f};  // 4 independent softmax-denom partials
  bf16x8 pa[2];          // packed P fragments carried body->body

  // DMA one K/V tile with 512 threads:
  // K = 832 chunks [64 rows][13 slots] (slot s holds chunk min(s,11));
  // V = 768 chunks [96 rows][8 slots]  (slot s holds chunk (s^row)&7).
  auto stage = [&](int kt, int kb_, int vb_) {
    u16* kd = smem + kb_ * 6656;
    u16* vd = smem + 13312 + vb_ * 6144;
    {
      int sl = tid;                        // 0..511
      int row = sl / 13, s = sl - row * 13;
      int c = s > 11 ? 11 : s;
      async16(KpB + (size_t)(kt + row) * QKVN + c * 8, kd + sl * 8);
    }
    if (tid < 320) {
      int sl = 512 + tid;                  // 512..831
      int row = sl / 13, s = sl - row * 13;
      int c = s > 11 ? 11 : s;
      async16(KpB + (size_t)(kt + row) * QKVN + c * 8, kd + sl * 8);
    }
    {
      int s = tid;
      int row = s >> 3, c = (s ^ row) & 7;
      async16(VtB + (size_t)row * SEQ + kt + c * 8, vd + s * 8);
    }
    if (tid < 256) {
      int s = 512 + tid;
      int row = s >> 3, c = (s ^ row) & 7;
      async16(VtB + (size_t)row * SEQ + kt + c * 8, vd + s * 8);
    }
  };

  stage(0, 0, 0);
  int vs = 1;   // V-buf for next stage (tile t+1)
  int vr = 0;   // V-buf for PV read (tile t-1)
  const int krow = kodd * 32 + l32;

  for (int t = 0; t < 32; t++) {
    __syncthreads();  // drains DMA of tile t; protects bufs being re-staged
    if (t + 1 < 32) stage((t + 1) * 64, (t + 1) & 1, vs);
    vs = (vs == 2) ? 0 : vs + 1;

    // QK(t): S^T = K Q^T for this wave's 32-key half; col = q
    const u16* kd = smem + (t & 1) * 6656;
    f32x16 sc = {};
    __builtin_amdgcn_s_setprio(1);
#pragma unroll
    for (int d = 0; d < 6; d++) {
      bf16x8 kb = ld8(&kd[krow * KROW + (d * 2 + half) * 8]);  // identity slot
      sc = __builtin_amdgcn_mfma_f32_32x32x16_bf16(kb, qf[d], sc, 0, 0, 0);
    }

    // PV(t-1): O^T += V^T P^T (independent of QK(t) -> overlaps)
    if (t > 0) {
      const u16* vd = smem + 13312 + vr * 6144;
      vr = (vr == 2) ? 0 : vr + 1;
#pragma unroll
      for (int ks = 0; ks < 2; ks++) {
        int gv = kodd * 4 + ks * 2 + half;
#pragma unroll
        for (int db = 0; db < 3; db++) {
          int vrow = db * 32 + l32;
          bf16x8 va = ld8(&vd[vrow * VROW + ((gv ^ vrow) & 7) * 8]);
          of[db] = __builtin_amdgcn_mfma_f32_32x32x16_bf16(va, pa[ks], of[db], 0, 0, 0);
        }
      }
    }
    __builtin_amdgcn_s_setprio(0);

    // SM(t): P = exp2(s*cs - Ms); 4 independent l chains; pack into pa
#pragma unroll
    for (int r = 0; r < 16; r++) {
      float p = __builtin_amdgcn_exp2f(sc[r] * cs - Ms);
      lp[r & 3] += p;
      sc[r] = p;
    }
    PACK_SLICE(sc, 0, pa[0])
    PACK_SLICE(sc, 8, pa[1])
  }

  // tail: PV(31) (V[31%3=1] staged & drained; no writer follows)
  {
    const u16* vd = smem + 13312 + vr * 6144;
#pragma unroll
    for (int ks = 0; ks < 2; ks++) {
      int gv = kodd * 4 + ks * 2 + half;
#pragma unroll
      for (int db = 0; db < 3; db++) {
        int vrow = db * 32 + l32;
        bf16x8 va = ld8(&vd[vrow * VROW + ((gv ^ vrow) & 7) * 8]);
        of[db] = __builtin_amdgcn_mfma_f32_32x32x16_bf16(va, pa[ks], of[db], 0, 0, 0);
      }
    }
  }

  // ---- epilogue: wave-pair combine via LDS, divide, store ----
  float l_lane = (lp[0] + lp[1]) + (lp[2] + lp[3]);
  float lw = l_lane + __shfl_xor(l_lane, 32);   // this wave's l per q=l32
  float linv = 0.f;
  float* xf = (float*)smem;
  const int q = q0 + l32;
  u16* Orow = Ob + (size_t)(b * SEQ + q) * DM + h * DK;

  __syncthreads();                               // S1: loop done, smem free
  if (kodd) {                                    // phase A write: of[0,1] + lw
    float* dst = xf + (pair * 64 + lane) * 33;
#pragma unroll
    for (int r = 0; r < 16; r++) { dst[r] = of[0][r]; dst[16 + r] = of[1][r]; }
    dst[32] = lw;
  }
  __syncthreads();                               // S2
  if (!kodd) {
    const float* src = xf + (pair * 64 + lane) * 33;
    linv = 1.f / (lw + src[32]);
#pragma unroll
    for (int db = 0; db < 2; db++)
#pragma unroll
      for (int r = 0; r < 16; r++) {
        int dk = db * 32 + (r & 3) + 8 * (r >> 2) + 4 * half;
        Orow[dk] = f2bf((of[db][r] + src[db * 16 + r]) * linv);
      }
  }
  __syncthreads();                               // S3: phase A reads done
  if (kodd) {                                    // phase B write: of[2]
    float* dst = xf + (pair * 64 + lane) * 16;
#pragma unroll
    for (int r = 0; r < 16; r++) dst[r] = of[2][r];
  }
  __syncthreads();                               // S4
  if (!kodd) {
    const float* src = xf + (pair * 64 + lane) * 16;
#pragma unroll
    for (int r = 0; r < 16; r++) {
      int dk = 64 + (r & 3) + 8 * (r >> 2) + 4 * half;
      Orow[dk] = f2bf((of[2][r] + src[r]) * linv);
    }
  }
}

// ---------- LayerNorm: out = LN(y); outf and/or outb optional ----------
__global__ __launch_bounds__(256)
void ln_kernel(const float* __restrict__ y, const float* __restrict__ g,
               const float* __restrict__ be, float* __restrict__ outf,
               u16* __restrict__ outb) {
  int row = blockIdx.x, t = threadIdx.x;
  const float* yr = y + (size_t)row * DM;
  float v[3], s = 0.f, s2 = 0.f;
#pragma unroll
  for (int i = 0; i < 3; i++) {
    v[i] = yr[t + i * 256];
    s += v[i];
    s2 += v[i] * v[i];
  }
#pragma unroll
  for (int m = 1; m < 64; m <<= 1) {
    s += __shfl_xor(s, m);
    s2 += __shfl_xor(s2, m);
  }
  __shared__ float red[2][4];
  int w = t >> 6;
  if ((t & 63) == 0) { red[0][w] = s; red[1][w] = s2; }
  __syncthreads();
  s = red[0][0] + red[0][1] + red[0][2] + red[0][3];
  s2 = red[1][0] + red[1][1] + red[1][2] + red[1][3];
  float mu = s * (1.f / DM);
  float var = s2 * (1.f / DM) - mu * mu;
  float rs = rsqrtf(var + 1e-5f);
#pragma unroll
  for (int i = 0; i < 3; i++) {
    int e = t + i * 256;
    float o = (v[i] - mu) * rs * g[e] + be[e];
    if (outf) outf[(size_t)row * DM + e] = o;
    if (outb) outb[(size_t)row * DM + e] = f2bf(o);
  }
}

// ---------- workspace layout (bytes) ----------
#define SZ_BF 12582912ull            // 8192*768*2
#define SZ_F  25165824ull            // 8192*768*4
#define O_XB   0ull                                  // x bf16; later attn_out
#define O_WT   (O_XB + SZ_BF)                        // qkv^T concat [2304][768] bf16
#define O_WOT  (O_WT + 3538944ull)
#define O_W1T  (O_WOT + 1179648ull)
#define O_W2T  (O_W1T + 3145728ull)
#define O_QKV  (O_W2T + 3145728ull)                  // [8192][2304] bf16; later x1b + h
#define O_VT   (O_QKV + 37748736ull)                 // [32][96][2048] bf16
#define O_Y    (O_VT + SZ_BF)                        // fp32 pre-LN buffer
#define O_X1F  (O_Y + SZ_F)                          // (unused now)
#define O_BIAS (O_X1F + SZ_F)                        // 2304 fp32 concat qkv bias

extern "C" void kernel_launch(void* const* d_in, const int* in_sizes, int n_in,
                              void* d_out, int out_size, void* d_ws, size_t ws_size,
                              hipStream_t stream) {
  const float* x   = (const float*)d_in[0];
  const float* Wq  = (const float*)d_in[1];
  const float* bq  = (const float*)d_in[2];
  const float* Wk  = (const float*)d_in[3];
  const float* bk  = (const float*)d_in[4];
  const float* Wv  = (const float*)d_in[5];
  const float* bv  = (const float*)d_in[6];
  const float* Wo  = (const float*)d_in[7];
  const float* bo  = (const float*)d_in[8];
  const float* g1  = (const float*)d_in[9];
  const float* be1 = (const float*)d_in[10];
  const float* W1  = (const float*)d_in[11];
  const float* b1  = (const float*)d_in[12];
  const float* W2  = (const float*)d_in[13];
  const float* b2  = (const float*)d_in[14];
  const float* g2  = (const float*)d_in[15];
  const float* be2 = (const float*)d_in[16];
  float* out = (float*)d_out;
  char* ws = (char*)d_ws;

  u16* xb    = (u16*)(ws + O_XB);
  u16* WT    = (u16*)(ws + O_WT);
  u16* WoT   = (u16*)(ws + O_WOT);
  u16* W1T   = (u16*)(ws + O_W1T);
  u16* W2T   = (u16*)(ws + O_W2T);
  u16* qkv   = (u16*)(ws + O_QKV);
  u16* vt    = (u16*)(ws + O_VT);
  float* y   = (float*)(ws + O_Y);
  float* bqkv = (float*)(ws + O_BIAS);
  u16* ao   = xb;                       // alias: xb dead after QKV GEMM
  u16* x1b  = qkv;                      // alias: qkv dead after attention
  u16* hbuf = qkv + (size_t)MTOK * DM;  // h [8192][2048] bf16

  // fused prep (one dispatch)
  prep<<<11529, 256, 0, stream>>>(x, xb, bq, bk, bv, bqkv,
                                  Wq, Wk, Wv, Wo, W1, W2,
                                  WT, WoT, W1T, W2T);

  // QKV projection (fused N=2304): 18x64 tiles, XCD-swizzled 1-D grid
  gemm_bt<0, 0, 1><<<1152, 256, 0, stream>>>(xb, WT, bqkv, nullptr, nullptr, qkv, QKVN, DM);
  // V^T for PV A-operand
  transpose_v<<<dim3(64, 3, 32), dim3(32, 8), 0, stream>>>(qkv + 1536, vt);
  // attention: 512 blocks x 512 threads (8 waves: 4 q-subs x 2 key-halves)
  flash_attn<<<512, 512, 0, stream>>>(qkv, vt, ao);
  // out projection + residual(x fp32) -> y (fp32): 12x64 tiles, swizzled
  gemm_bt64<1, 0, 0, 0><<<768, 256, 0, stream>>>(ao, WoT, bo, x, nullptr, y, nullptr, DM, DM);
  // LN1 -> x1b (bf16 only; fp32 x1 round-trip eliminated)
  ln_kernel<<<8192, 256, 0, stream>>>(y, g1, be1, nullptr, x1b);
  // FFN1 + ReLU -> h (bf16): 16x64 tiles, swizzled
  gemm_bt<0, 1, 1><<<1024, 256, 0, stream>>>(x1b, W1T, b1, nullptr, nullptr, hbuf, DFF, DM);
  // FFN2 + residual(x1b bf16) -> y (fp32): 12x64 tiles, swizzled
  gemm_bt64<1, 0, 0, 1><<<768, 256, 0, stream>>>(hbuf, W2T, b2, nullptr, x1b, y, nullptr, DM, DFF);
  // LN2 -> out
  ln_kernel<<<8192, 256, 0, stream>>>(y, g2, be2, out, nullptr);
}